// Round 8
// baseline (83.366 us; speedup 1.0000x reference)
//
#include <hip/hip_runtime.h>

#define NTOK 2048

typedef __attribute__((ext_vector_type(8))) short s8v;
typedef __attribute__((ext_vector_type(4))) float f32x4;

__device__ inline unsigned short f2bf(float f) {
  unsigned u = __builtin_bit_cast(unsigned, f);
  u += 0x7FFFu + ((u >> 16) & 1u);
  return (unsigned short)(u >> 16);
}
__device__ inline unsigned fkey(float f) {
  unsigned u = __builtin_bit_cast(unsigned, f);
  return (u & 0x80000000u) ? ~u : (u | 0x80000000u);
}
__device__ inline float kdec(unsigned k) {
  unsigned u = (k & 0x80000000u) ? (k ^ 0x80000000u) : ~k;
  return __builtin_bit_cast(float, u);
}

// ---- Kernel 0: init the atomic min/max cells (graph-capture safe) ----
__global__ void gat_init(unsigned* gmaxk, unsigned* gmink) {
  int t = threadIdx.x;
  if (t < 8) { gmaxk[t] = 0u; gmink[t] = 0xFFFFFFFFu; }
}

// ---- Kernel A: Wh = h@W, f1/f2 = Wh@a1/a2, WhT = bf16(Wh)^T, f2 min/max ----
__global__ __launch_bounds__(256) void gat_pre(
    const float* __restrict__ h, const float* __restrict__ W,
    const float* __restrict__ a, unsigned short* __restrict__ WhT,
    float* __restrict__ f1, float* __restrict__ f2,
    unsigned* __restrict__ gmaxk, unsigned* __restrict__ gmink) {
  __shared__ float wL[128 * 64];            // 32 KB
  __shared__ float hL[64 * 128];            // 32 KB
  __shared__ unsigned short tL[64 * 66];    // 8.25 KB [feat][tok] pad 66
  __shared__ float bmx[4], bmn[4];
  int t = threadIdx.x;
  {
    const float4* W4 = (const float4*)W;
    float4* wL4 = (float4*)wL;
#pragma unroll
    for (int k = 0; k < 8; ++k) wL4[t + 256 * k] = W4[t + 256 * k];
    const float4* h4 = (const float4*)(h + (size_t)blockIdx.x * 64 * 128);
    float4* hL4 = (float4*)hL;
#pragma unroll
    for (int k = 0; k < 8; ++k) hL4[t + 256 * k] = h4[t + 256 * k];
  }
  __syncthreads();
  int w = t >> 6, lane = t & 63;
  float acc[16];
#pragma unroll
  for (int r = 0; r < 16; ++r) acc[r] = 0.f;
  for (int kc = 0; kc < 128; kc += 32) {
    float wreg[32];
#pragma unroll
    for (int kk = 0; kk < 32; ++kk) wreg[kk] = wL[(kc + kk) * 64 + lane];
#pragma unroll
    for (int r = 0; r < 16; ++r) {
      const float* hrow = &hL[(w * 16 + r) * 128 + kc];
#pragma unroll
      for (int kk = 0; kk < 32; kk += 4) {
        float4 hv = *(const float4*)(hrow + kk);
        acc[r] += hv.x * wreg[kk] + hv.y * wreg[kk + 1] +
                  hv.z * wreg[kk + 2] + hv.w * wreg[kk + 3];
      }
    }
  }
  float a1 = a[lane], a2 = a[lane + 64];
  int row0 = blockIdx.x * 64 + w * 16;
  float wmx = -3.4e38f, wmn = 3.4e38f;
#pragma unroll
  for (int r = 0; r < 16; ++r) {
    float v1 = acc[r] * a1, v2 = acc[r] * a2;
#pragma unroll
    for (int s = 32; s; s >>= 1) {
      v1 += __shfl_xor(v1, s, 64);
      v2 += __shfl_xor(v2, s, 64);
    }
    if (lane == 0) { f1[row0 + r] = v1; f2[row0 + r] = v2; }
    wmx = fmaxf(wmx, v2);
    wmn = fminf(wmn, v2);
    tL[lane * 66 + w * 16 + r] = f2bf(acc[r]);
  }
  if (lane == 0) { bmx[w] = wmx; bmn[w] = wmn; }
  __syncthreads();
  int b = blockIdx.x >> 5;  // 32 blocks per batch
  if (t == 0) {
    float mx = fmaxf(fmaxf(bmx[0], bmx[1]), fmaxf(bmx[2], bmx[3]));
    float mn = fminf(fminf(bmn[0], bmn[1]), fminf(bmn[2], bmn[3]));
    atomicMax(&gmaxk[b], fkey(mx));
    atomicMin(&gmink[b], fkey(mn));
  }
  // WhT[b][feat][tok] write: 4 threads per feature, 64B-contiguous segments
  int tok0 = (blockIdx.x & 31) * 64;
  int f = t >> 2, sub = t & 3;
  const unsigned short* src = &tL[f * 66];
  unsigned short* dst = WhT + ((size_t)b * 64 + f) * NTOK + tok0;
  *(uint4*)(dst + sub * 8) = *(const uint4*)(src + sub * 8);
  *(uint4*)(dst + 32 + sub * 8) = *(const uint4*)(src + 32 + sub * 8);
}

// ---- Kernel B: async global_load_lds adj staging + fused softmax+PV ----
// grid (128,8), 256 thr = 4 waves, 16 rows/block. K split into 8 stages of
// 256; stage = 16 rows x 1KB raw adj DMA'd to LDS (dbuf), XOR-swizzled via
// pre-swizzled per-lane SOURCE address (LDS dest stays linear). Counted
// vmcnt keeps next stage's DMA in flight across raw s_barriers. Wave w
// computes chunks {2w,2w+1} (K=32 each) of every stage; lane (l15,lhi):
// A-frag row=l15, k=ch*32+lhi*8+q. Row-sum via all-ones B-fragment MFMA.
#define GLD16(g, l)                                              \
  __builtin_amdgcn_global_load_lds(                              \
      (const __attribute__((address_space(1))) void*)(g),        \
      (__attribute__((address_space(3))) void*)(l), 16, 0, 0)

__global__ __launch_bounds__(256, 3) void gat_main(
    const int* __restrict__ adj, const unsigned short* __restrict__ WhT,
    const float* __restrict__ f1, const float* __restrict__ f2,
    const unsigned* __restrict__ gmaxk, const unsigned* __restrict__ gmink,
    float* __restrict__ out) {
  __shared__ __align__(16) int aL[2][16][256];  // 2 x 16 KB raw adj stages
  __shared__ float red[4 * 16 * 68];            // [wave][row][feat pad 68]
  __shared__ float sums[4 * 16];
  int t = threadIdx.x;
  int b = blockIdx.y;
  int i0 = blockIdx.x * 16;
  int w = t >> 6, lane = t & 63, l15 = lane & 15, lhi = lane >> 4;

  const float L2E = 1.44269504f;
  float f1s = f1[(size_t)b * NTOK + i0 + l15] * L2E;
  float gmx = kdec(gmaxk[b]), gmn = kdec(gmink[b]);
  float mr = fmaxf(f1s * gmx, f1s * gmn);
  float ms = fmaxf(mr, 0.01f * mr);  // log2-scaled leaky upper bound

  const int* abase = adj + ((size_t)b * NTOK + i0) * NTOK;
  const float* f2p = f2 + (size_t)b * NTOK;
  const unsigned short* bp0 = WhT + (size_t)b * 64 * NTOK + (size_t)l15 * NTOK;
  int xr = (l15 & 7) << 4;

  const s8v bones = {0x3F80, 0x3F80, 0x3F80, 0x3F80, 0x3F80, 0x3F80, 0x3F80, 0x3F80};
  f32x4 ac0 = {0.f, 0.f, 0.f, 0.f}, ac1 = ac0, ac2 = ac0, ac3 = ac0, ac4 = ac0;

  // stage issue: wave w DMAs rows w*4..w*4+3; per-lane source pre-swizzled
#define ISSUE(ss, bb)                                                         \
  {                                                                           \
    _Pragma("unroll") for (int j = 0; j < 4; ++j) {                           \
      int row = w * 4 + j;                                                    \
      const char* g = (const char*)(abase + (size_t)row * NTOK + (ss) * 256) +\
                      ((lane * 16) ^ ((row & 7) << 4));                       \
      GLD16(g, &aL[bb][row][0]);                                              \
    }                                                                         \
  }

  ISSUE(0, 0);
  ISSUE(1, 1);

#pragma unroll
  for (int s = 0; s < 8; ++s) {
    if (s < 7) asm volatile("s_waitcnt vmcnt(4)" ::: "memory");
    else       asm volatile("s_waitcnt vmcnt(0)" ::: "memory");
    __builtin_amdgcn_sched_barrier(0);
    __builtin_amdgcn_s_barrier();
    __builtin_amdgcn_sched_barrier(0);
    const char* lp = (const char*)&aL[s & 1][0][0];
#pragma unroll
    for (int cc = 0; cc < 2; ++cc) {
      int ch = w * 2 + cc;
      int off = ch * 128 + lhi * 32;
      int4 ra = *(const int4*)(lp + l15 * 1024 + (off ^ xr));
      int4 rb = *(const int4*)(lp + l15 * 1024 + ((off + 16) ^ xr));
      int kg = s * 256 + ch * 32 + lhi * 8;
      float4 v0 = *(const float4*)(f2p + kg);
      float4 v1 = *(const float4*)(f2p + kg + 4);
      const unsigned short* bp = bp0 + kg;
      s8v bf0 = *(const s8v*)(bp);
      s8v bf1 = *(const s8v*)(bp + 16 * NTOK);
      s8v bf2 = *(const s8v*)(bp + 32 * NTOK);
      s8v bf3 = *(const s8v*)(bp + 48 * NTOK);
      float sv[8] = {f1s * v0.x, f1s * v0.y, f1s * v0.z, f1s * v0.w,
                     f1s * v1.x, f1s * v1.y, f1s * v1.z, f1s * v1.w};
      int am[8] = {ra.x, ra.y, ra.z, ra.w, rb.x, rb.y, rb.z, rb.w};
      s8v af;
#pragma unroll
      for (int q = 0; q < 8; ++q) {
        float sc = sv[q];
        float lk = fmaxf(sc, 0.01f * sc);
#if __has_builtin(__builtin_amdgcn_exp2f)
        float pe = __builtin_amdgcn_exp2f(lk - ms);
#else
        float pe = exp2f(lk - ms);
#endif
        float p = am[q] > 0 ? pe : 0.f;
        unsigned uu = __builtin_bit_cast(unsigned, p) + 0x8000u;
        af[q] = (short)(uu >> 16);
      }
      ac0 = __builtin_amdgcn_mfma_f32_16x16x32_bf16(af, bf0, ac0, 0, 0, 0);
      ac1 = __builtin_amdgcn_mfma_f32_16x16x32_bf16(af, bf1, ac1, 0, 0, 0);
      ac2 = __builtin_amdgcn_mfma_f32_16x16x32_bf16(af, bf2, ac2, 0, 0, 0);
      ac3 = __builtin_amdgcn_mfma_f32_16x16x32_bf16(af, bf3, ac3, 0, 0, 0);
      ac4 = __builtin_amdgcn_mfma_f32_16x16x32_bf16(af, bones, ac4, 0, 0, 0);
    }
    __builtin_amdgcn_sched_barrier(0);
    __builtin_amdgcn_s_barrier();
    __builtin_amdgcn_sched_barrier(0);
    if (s < 6) ISSUE(s + 2, s & 1);
  }
#undef ISSUE

  // C partials: row = lhi*4+reg, col(feat) = ft*16+l15; row-sums from ac4
#pragma unroll
  for (int reg = 0; reg < 4; ++reg) {
    int row = lhi * 4 + reg;
    float* dst = &red[w * 1088 + row * 68 + l15];
    dst[0] = ac0[reg];
    dst[16] = ac1[reg];
    dst[32] = ac2[reg];
    dst[48] = ac3[reg];
    if (l15 == 0) sums[w * 16 + row] = ac4[reg];
  }
  __syncthreads();

  // epilogue: 1024 outputs / 256 threads
#pragma unroll
  for (int rep = 0; rep < 4; ++rep) {
    int idx = t + rep * 256;
    int mm = idx >> 6, f = idx & 63;
    float v = 0.f, dn = 0.f;
#pragma unroll
    for (int w2 = 0; w2 < 4; ++w2) {
      v += red[w2 * 1088 + mm * 68 + f];
      dn += sums[w2 * 16 + mm];
    }
    float rdn = dn > 0.f ? 1.0f / dn : 0.f;
    float hp = v * rdn;
    float o = hp > 0.f ? hp : expm1f(hp);
    out[((size_t)b * NTOK + i0 + mm) * 64 + f] = o;
  }
}

extern "C" void kernel_launch(void* const* d_in, const int* in_sizes, int n_in,
                              void* d_out, int out_size, void* d_ws, size_t ws_size,
                              hipStream_t stream) {
  const float* h = (const float*)d_in[0];
  const int* adj = (const int*)d_in[1];
  const float* W = (const float*)d_in[2];
  const float* a = (const float*)d_in[3];
  float* out = (float*)d_out;

  unsigned short* WhT = (unsigned short*)d_ws;              // 2 MB
  float* f1 = (float*)((char*)d_ws + 2 * 1024 * 1024);      // 64 KB
  float* f2 = f1 + 16384;                                   // 64 KB
  unsigned* gmaxk = (unsigned*)(f2 + 16384);                // 32 B
  unsigned* gmink = gmaxk + 8;                              // 32 B

  gat_init<<<1, 64, 0, stream>>>(gmaxk, gmink);
  gat_pre<<<256, 256, 0, stream>>>(h, W, a, WhT, f1, f2, gmaxk, gmink);
  gat_main<<<dim3(128, 8), 256, 0, stream>>>(adj, WhT, f1, f2, gmaxk, gmink, out);
}

// Round 9
// 82.381 us; speedup vs baseline: 1.0120x; 1.0120x over previous
//
#include <hip/hip_runtime.h>

#define NTOK 2048

typedef __attribute__((ext_vector_type(8))) short s8v;
typedef __attribute__((ext_vector_type(4))) float f32x4;

__device__ inline unsigned short f2bf(float f) {
  unsigned u = __builtin_bit_cast(unsigned, f);
  u += 0x7FFFu + ((u >> 16) & 1u);
  return (unsigned short)(u >> 16);
}
__device__ inline unsigned fkey(float f) {
  unsigned u = __builtin_bit_cast(unsigned, f);
  return (u & 0x80000000u) ? ~u : (u | 0x80000000u);
}
__device__ inline float kdec(unsigned k) {
  unsigned u = (k & 0x80000000u) ? (k ^ 0x80000000u) : ~k;
  return __builtin_bit_cast(float, u);
}

// ---- Kernel 0: init the atomic min/max cells (graph-capture safe) ----
__global__ void gat_init(unsigned* gmaxk, unsigned* gmink) {
  int t = threadIdx.x;
  if (t < 8) { gmaxk[t] = 0u; gmink[t] = 0xFFFFFFFFu; }
}

// ---- Kernel A: Wh = h@W, f1/f2 = Wh@a1/a2, WhT = bf16(Wh)^T, f2 min/max ----
__global__ __launch_bounds__(256) void gat_pre(
    const float* __restrict__ h, const float* __restrict__ W,
    const float* __restrict__ a, unsigned short* __restrict__ WhT,
    float* __restrict__ f1, float* __restrict__ f2,
    unsigned* __restrict__ gmaxk, unsigned* __restrict__ gmink) {
  __shared__ float wL[128 * 64];            // 32 KB
  __shared__ float hL[64 * 128];            // 32 KB
  __shared__ unsigned short tL[64 * 66];    // 8.25 KB [feat][tok] pad 66
  __shared__ float bmx[4], bmn[4];
  int t = threadIdx.x;
  {
    const float4* W4 = (const float4*)W;
    float4* wL4 = (float4*)wL;
#pragma unroll
    for (int k = 0; k < 8; ++k) wL4[t + 256 * k] = W4[t + 256 * k];
    const float4* h4 = (const float4*)(h + (size_t)blockIdx.x * 64 * 128);
    float4* hL4 = (float4*)hL;
#pragma unroll
    for (int k = 0; k < 8; ++k) hL4[t + 256 * k] = h4[t + 256 * k];
  }
  __syncthreads();
  int w = t >> 6, lane = t & 63;
  float acc[16];
#pragma unroll
  for (int r = 0; r < 16; ++r) acc[r] = 0.f;
  for (int kc = 0; kc < 128; kc += 32) {
    float wreg[32];
#pragma unroll
    for (int kk = 0; kk < 32; ++kk) wreg[kk] = wL[(kc + kk) * 64 + lane];
#pragma unroll
    for (int r = 0; r < 16; ++r) {
      const float* hrow = &hL[(w * 16 + r) * 128 + kc];
#pragma unroll
      for (int kk = 0; kk < 32; kk += 4) {
        float4 hv = *(const float4*)(hrow + kk);
        acc[r] += hv.x * wreg[kk] + hv.y * wreg[kk + 1] +
                  hv.z * wreg[kk + 2] + hv.w * wreg[kk + 3];
      }
    }
  }
  float a1 = a[lane], a2 = a[lane + 64];
  int row0 = blockIdx.x * 64 + w * 16;
  float wmx = -3.4e38f, wmn = 3.4e38f;
#pragma unroll
  for (int r = 0; r < 16; ++r) {
    float v1 = acc[r] * a1, v2 = acc[r] * a2;
#pragma unroll
    for (int s = 32; s; s >>= 1) {
      v1 += __shfl_xor(v1, s, 64);
      v2 += __shfl_xor(v2, s, 64);
    }
    if (lane == 0) { f1[row0 + r] = v1; f2[row0 + r] = v2; }
    wmx = fmaxf(wmx, v2);
    wmn = fminf(wmn, v2);
    tL[lane * 66 + w * 16 + r] = f2bf(acc[r]);
  }
  if (lane == 0) { bmx[w] = wmx; bmn[w] = wmn; }
  __syncthreads();
  int b = blockIdx.x >> 5;  // 32 blocks per batch
  if (t == 0) {
    float mx = fmaxf(fmaxf(bmx[0], bmx[1]), fmaxf(bmx[2], bmx[3]));
    float mn = fminf(fminf(bmn[0], bmn[1]), fminf(bmn[2], bmn[3]));
    atomicMax(&gmaxk[b], fkey(mx));
    atomicMin(&gmink[b], fkey(mn));
  }
  // WhT[b][feat][tok] write: 4 threads per feature, 64B-contiguous segments
  int tok0 = (blockIdx.x & 31) * 64;
  int f = t >> 2, sub = t & 3;
  const unsigned short* src = &tL[f * 66];
  unsigned short* dst = WhT + ((size_t)b * 64 + f) * NTOK + tok0;
  *(uint4*)(dst + sub * 8) = *(const uint4*)(src + sub * 8);
  *(uint4*)(dst + 32 + sub * 8) = *(const uint4*)(src + 32 + sub * 8);
}

// ---- Kernel B: split-K fused kernel. grid (128, 8, 2): 16 rows x half-K. ----
// Phase A: each wave streams 4 adj half-rows with 16-deep forced load batches
// + __ballot bitpack (1 instr per 64 edges) -> 2 KB LDS mask (linear layout,
// padded stride 136). Phase B: exp-in-fragment-layout + bf16 MFMA with
// all-ones denominator column (R8 math, unchanged). Partials -> global;
// gat_fin reduces halves, normalizes, ELU.
__global__ __launch_bounds__(256, 6) void gat_main(
    const int* __restrict__ adj, const unsigned short* __restrict__ WhT,
    const float* __restrict__ f1, const float* __restrict__ f2,
    const unsigned* __restrict__ gmaxk, const unsigned* __restrict__ gmink,
    float* __restrict__ part, float* __restrict__ dsum) {
  __shared__ unsigned char mLDS[16 * 136];  // 2.1 KB bitmask, stride 136
  __shared__ float red[4 * 16 * 68];        // 17.4 KB
  __shared__ float sums[4 * 16];
  int t = threadIdx.x;
  int gx = blockIdx.x, b = blockIdx.y, hh = blockIdx.z;
  int i0 = gx * 16;
  int w = t >> 6, lane = t & 63, l15 = lane & 15, lhi = lane >> 4;

  // ---- phase A: pure stream + ballot pack ----
  {
    const int* abase = adj + ((size_t)b * NTOK + i0) * NTOK + hh * 1024;
    for (int j = 0; j < 4; ++j) {
      int r = w * 4 + j;
      const int* arow = abase + (size_t)r * NTOK;
      int v[16];
#pragma unroll
      for (int c = 0; c < 16; ++c) v[c] = arow[c * 64 + lane];
      __builtin_amdgcn_sched_barrier(0);  // keep all 16 loads issued & in flight
#pragma unroll
      for (int c = 0; c < 16; ++c) {
        unsigned long long bb = __ballot(v[c] > 0);
        if (lane == 0) *(unsigned long long*)&mLDS[r * 136 + c * 8] = bb;
      }
    }
  }

  const float L2E = 1.44269504f;
  float f1s = f1[(size_t)b * NTOK + i0 + l15] * L2E;
  float gmx = kdec(gmaxk[b]), gmn = kdec(gmink[b]);
  float mr = fmaxf(f1s * gmx, f1s * gmn);
  float ms = fmaxf(mr, 0.01f * mr);  // log2-scaled safe upper bound

  __syncthreads();

  // ---- phase B: fused exp + MFMA over this half's K ----
  const float* f2p = f2 + (size_t)b * NTOK + hh * 1024;
  const unsigned short* bp0 =
      WhT + (size_t)b * 64 * NTOK + (size_t)l15 * NTOK + hh * 1024;
  const s8v bones = {0x3F80, 0x3F80, 0x3F80, 0x3F80, 0x3F80, 0x3F80, 0x3F80, 0x3F80};
  f32x4 ac0 = {0.f, 0.f, 0.f, 0.f}, ac1 = ac0, ac2 = ac0, ac3 = ac0, ac4 = ac0;

#pragma unroll
  for (int cc = 0; cc < 8; ++cc) {
    int ch = w * 8 + cc;               // chunk within the half (K=32 each)
    int kl = ch * 32 + lhi * 8;        // k offset within half for this lane
    float4 v0 = *(const float4*)(f2p + kl);
    float4 v1 = *(const float4*)(f2p + kl + 4);
    const unsigned short* bp = bp0 + kl;
    s8v bf0 = *(const s8v*)(bp);
    s8v bf1 = *(const s8v*)(bp + 16 * NTOK);
    s8v bf2 = *(const s8v*)(bp + 32 * NTOK);
    s8v bf3 = *(const s8v*)(bp + 48 * NTOK);
    unsigned byte = mLDS[l15 * 136 + ch * 4 + lhi];

    float sv[8] = {f1s * v0.x, f1s * v0.y, f1s * v0.z, f1s * v0.w,
                   f1s * v1.x, f1s * v1.y, f1s * v1.z, f1s * v1.w};
    s8v af;
#pragma unroll
    for (int q = 0; q < 8; ++q) {
      float sc = sv[q];
      float lk = fmaxf(sc, 0.01f * sc);
#if __has_builtin(__builtin_amdgcn_exp2f)
      float pe = __builtin_amdgcn_exp2f(lk - ms);
#else
      float pe = exp2f(lk - ms);
#endif
      float p = (byte & (1u << q)) ? pe : 0.f;
      unsigned uu = __builtin_bit_cast(unsigned, p) + 0x8000u;
      af[q] = (short)(uu >> 16);
    }
    ac0 = __builtin_amdgcn_mfma_f32_16x16x32_bf16(af, bf0, ac0, 0, 0, 0);
    ac1 = __builtin_amdgcn_mfma_f32_16x16x32_bf16(af, bf1, ac1, 0, 0, 0);
    ac2 = __builtin_amdgcn_mfma_f32_16x16x32_bf16(af, bf2, ac2, 0, 0, 0);
    ac3 = __builtin_amdgcn_mfma_f32_16x16x32_bf16(af, bf3, ac3, 0, 0, 0);
    ac4 = __builtin_amdgcn_mfma_f32_16x16x32_bf16(af, bones, ac4, 0, 0, 0);
  }

  // C partials: row = lhi*4+reg, col(feat) = ft*16+l15; row-sums from ac4
#pragma unroll
  for (int reg = 0; reg < 4; ++reg) {
    int row = lhi * 4 + reg;
    float* dst = &red[w * 1088 + row * 68 + l15];
    dst[0] = ac0[reg];
    dst[16] = ac1[reg];
    dst[32] = ac2[reg];
    dst[48] = ac3[reg];
    if (l15 == 0) sums[w * 16 + row] = ac4[reg];
  }
  __syncthreads();

  // write half-K partials (no normalization yet)
  size_t pb = (((size_t)b * 128 + gx) * 2 + hh);
#pragma unroll
  for (int rep = 0; rep < 4; ++rep) {
    int idx = t + rep * 256;
    int mm = idx >> 6, f = idx & 63;
    float v = 0.f, dn = 0.f;
#pragma unroll
    for (int w2 = 0; w2 < 4; ++w2) {
      v += red[w2 * 1088 + mm * 68 + f];
      dn += sums[w2 * 16 + mm];
    }
    part[pb * 1024 + mm * 64 + f] = v;
    if (f == 0) dsum[pb * 16 + mm] = dn;
  }
}

// ---- Kernel C: reduce the two K-halves, normalize, ELU ----
__global__ __launch_bounds__(256) void gat_fin(
    const float* __restrict__ part, const float* __restrict__ dsum,
    float* __restrict__ out) {
  int gx = blockIdx.x, b = blockIdx.y, t = threadIdx.x;
  size_t g = (size_t)b * 128 + gx;
#pragma unroll
  for (int rep = 0; rep < 4; ++rep) {
    int idx = t + rep * 256;
    int mm = idx >> 6, f = idx & 63;
    float v = part[(g * 2) * 1024 + mm * 64 + f] +
              part[(g * 2 + 1) * 1024 + mm * 64 + f];
    float dn = dsum[(g * 2) * 16 + mm] + dsum[(g * 2 + 1) * 16 + mm];
    float rdn = dn > 0.f ? 1.0f / dn : 0.f;
    float hp = v * rdn;
    float o = hp > 0.f ? hp : expm1f(hp);
    out[((size_t)b * NTOK + gx * 16 + mm) * 64 + f] = o;
  }
}

extern "C" void kernel_launch(void* const* d_in, const int* in_sizes, int n_in,
                              void* d_out, int out_size, void* d_ws, size_t ws_size,
                              hipStream_t stream) {
  const float* h = (const float*)d_in[0];
  const int* adj = (const int*)d_in[1];
  const float* W = (const float*)d_in[2];
  const float* a = (const float*)d_in[3];
  float* out = (float*)d_out;

  char* ws = (char*)d_ws;
  unsigned short* WhT = (unsigned short*)ws;            // 2 MB
  float* f1 = (float*)(ws + 2 * 1024 * 1024);           // 64 KB
  float* f2 = f1 + 16384;                               // 64 KB
  unsigned* gmaxk = (unsigned*)(f2 + 16384);            // 32 B
  unsigned* gmink = gmaxk + 8;                          // 32 B
  float* part = (float*)(ws + 3 * 1024 * 1024);         // 8 MB
  float* dsum = (float*)(ws + 12 * 1024 * 1024);        // 128 KB

  gat_init<<<1, 64, 0, stream>>>(gmaxk, gmink);
  gat_pre<<<256, 256, 0, stream>>>(h, W, a, WhT, f1, f2, gmaxk, gmink);
  gat_main<<<dim3(128, 8, 2), 256, 0, stream>>>(adj, WhT, f1, f2, gmaxk, gmink,
                                                part, dsum);
  gat_fin<<<dim3(128, 8), 256, 0, stream>>>(part, dsum, out);
}

// Round 10
// 72.484 us; speedup vs baseline: 1.1501x; 1.1365x over previous
//
#include <hip/hip_runtime.h>

#define NTOK 2048

typedef __attribute__((ext_vector_type(8))) short s8v;
typedef __attribute__((ext_vector_type(4))) float f32x4;

__device__ inline unsigned short f2bf(float f) {
  unsigned u = __builtin_bit_cast(unsigned, f);
  u += 0x7FFFu + ((u >> 16) & 1u);
  return (unsigned short)(u >> 16);
}
__device__ inline unsigned fkey(float f) {
  unsigned u = __builtin_bit_cast(unsigned, f);
  return (u & 0x80000000u) ? ~u : (u | 0x80000000u);
}
__device__ inline float kdec(unsigned k) {
  unsigned u = (k & 0x80000000u) ? (k ^ 0x80000000u) : ~k;
  return __builtin_bit_cast(float, u);
}

// ---- Kernel 0: init the atomic min/max cells (graph-capture safe) ----
__global__ void gat_init(unsigned* gmaxk, unsigned* gmink) {
  int t = threadIdx.x;
  if (t < 8) { gmaxk[t] = 0u; gmink[t] = 0xFFFFFFFFu; }
}

// ---- Kernel A: Wh = h@W, f1/f2 = Wh@a1/a2, WhT = bf16(Wh)^T, f2 min/max ----
__global__ __launch_bounds__(256) void gat_pre(
    const float* __restrict__ h, const float* __restrict__ W,
    const float* __restrict__ a, unsigned short* __restrict__ WhT,
    float* __restrict__ f1, float* __restrict__ f2,
    unsigned* __restrict__ gmaxk, unsigned* __restrict__ gmink) {
  __shared__ float wL[128 * 64];            // 32 KB
  __shared__ float hL[64 * 128];            // 32 KB
  __shared__ unsigned short tL[64 * 66];    // 8.25 KB [feat][tok] pad 66
  __shared__ float bmx[4], bmn[4];
  int t = threadIdx.x;
  {
    const float4* W4 = (const float4*)W;
    float4* wL4 = (float4*)wL;
#pragma unroll
    for (int k = 0; k < 8; ++k) wL4[t + 256 * k] = W4[t + 256 * k];
    const float4* h4 = (const float4*)(h + (size_t)blockIdx.x * 64 * 128);
    float4* hL4 = (float4*)hL;
#pragma unroll
    for (int k = 0; k < 8; ++k) hL4[t + 256 * k] = h4[t + 256 * k];
  }
  __syncthreads();
  int w = t >> 6, lane = t & 63;
  float acc[16];
#pragma unroll
  for (int r = 0; r < 16; ++r) acc[r] = 0.f;
  for (int kc = 0; kc < 128; kc += 32) {
    float wreg[32];
#pragma unroll
    for (int kk = 0; kk < 32; ++kk) wreg[kk] = wL[(kc + kk) * 64 + lane];
#pragma unroll
    for (int r = 0; r < 16; ++r) {
      const float* hrow = &hL[(w * 16 + r) * 128 + kc];
#pragma unroll
      for (int kk = 0; kk < 32; kk += 4) {
        float4 hv = *(const float4*)(hrow + kk);
        acc[r] += hv.x * wreg[kk] + hv.y * wreg[kk + 1] +
                  hv.z * wreg[kk + 2] + hv.w * wreg[kk + 3];
      }
    }
  }
  float a1 = a[lane], a2 = a[lane + 64];
  int row0 = blockIdx.x * 64 + w * 16;
  float wmx = -3.4e38f, wmn = 3.4e38f;
#pragma unroll
  for (int r = 0; r < 16; ++r) {
    float v1 = acc[r] * a1, v2 = acc[r] * a2;
#pragma unroll
    for (int s = 32; s; s >>= 1) {
      v1 += __shfl_xor(v1, s, 64);
      v2 += __shfl_xor(v2, s, 64);
    }
    if (lane == 0) { f1[row0 + r] = v1; f2[row0 + r] = v2; }
    wmx = fmaxf(wmx, v2);
    wmn = fminf(wmn, v2);
    tL[lane * 66 + w * 16 + r] = f2bf(acc[r]);
  }
  if (lane == 0) { bmx[w] = wmx; bmn[w] = wmn; }
  __syncthreads();
  int b = blockIdx.x >> 5;  // 32 blocks per batch
  if (t == 0) {
    float mx = fmaxf(fmaxf(bmx[0], bmx[1]), fmaxf(bmx[2], bmx[3]));
    float mn = fminf(fminf(bmn[0], bmn[1]), fminf(bmn[2], bmn[3]));
    atomicMax(&gmaxk[b], fkey(mx));
    atomicMin(&gmink[b], fkey(mn));
  }
  // WhT[b][feat][tok] write: 4 threads per feature, 64B-contiguous segments
  int tok0 = (blockIdx.x & 31) * 64;
  int f = t >> 2, sub = t & 3;
  const unsigned short* src = &tL[f * 66];
  unsigned short* dst = WhT + ((size_t)b * 64 + f) * NTOK + tok0;
  *(uint4*)(dst + sub * 8) = *(const uint4*)(src + sub * 8);
  *(uint4*)(dst + 32 + sub * 8) = *(const uint4*)(src + 32 + sub * 8);
}

// ---- Kernel B: split-K fused. grid (128,8,2), 256 thr = 4 waves. ----
// Phase A: ballot bitpack adj half-rows -> 2 KB LDS mask (R9, unchanged).
// Phase B: 8 k-tiles of 128; WhT tile (64f x 128k bf16, 16 KB) staged in LDS
// with XOR swizzle (f&7)<<4; per tile each wave computes one K=32 chunk
// entirely from LDS (ds_read_b128 B-frags) + exp-in-fragment-layout + 5 MFMAs
// (4 feature blocks + all-ones denominator column).
__global__ __launch_bounds__(256, 4) void gat_main(
    const int* __restrict__ adj, const unsigned short* __restrict__ WhT,
    const float* __restrict__ f1, const float* __restrict__ f2,
    const unsigned* __restrict__ gmaxk, const unsigned* __restrict__ gmink,
    float* __restrict__ part, float* __restrict__ dsum) {
  __shared__ unsigned char mLDS[16 * 136];              // 2.1 KB bitmask
  __shared__ __align__(16) unsigned char wTile[16384];  // 64f x 128k bf16
  __shared__ float red[4 * 16 * 68];                    // 17.4 KB
  __shared__ float sums[4 * 16];
  int t = threadIdx.x;
  int gx = blockIdx.x, b = blockIdx.y, hh = blockIdx.z;
  int i0 = gx * 16;
  int w = t >> 6, lane = t & 63, l15 = lane & 15, lhi = lane >> 4;

  // ---- phase A: pure stream + ballot pack ----
  {
    const int* abase = adj + ((size_t)b * NTOK + i0) * NTOK + hh * 1024;
    for (int j = 0; j < 4; ++j) {
      int r = w * 4 + j;
      const int* arow = abase + (size_t)r * NTOK;
      int v[16];
#pragma unroll
      for (int c = 0; c < 16; ++c) v[c] = arow[c * 64 + lane];
      __builtin_amdgcn_sched_barrier(0);  // keep the 16 loads batched
#pragma unroll
      for (int c = 0; c < 16; ++c) {
        unsigned long long bb = __ballot(v[c] > 0);
        if (lane == 0) *(unsigned long long*)&mLDS[r * 136 + c * 8] = bb;
      }
    }
  }

  const float L2E = 1.44269504f;
  float f1s = f1[(size_t)b * NTOK + i0 + l15] * L2E;
  float gmx = kdec(gmaxk[b]), gmn = kdec(gmink[b]);
  float mr = fmaxf(f1s * gmx, f1s * gmn);
  float ms = fmaxf(mr, 0.01f * mr);  // log2-scaled safe upper bound

  const float* f2p = f2 + (size_t)b * NTOK + hh * 1024;
  const unsigned short* WhB = WhT + (size_t)b * 64 * NTOK + hh * 1024;
  const s8v bones = {0x3F80, 0x3F80, 0x3F80, 0x3F80, 0x3F80, 0x3F80, 0x3F80, 0x3F80};
  f32x4 ac0 = {0.f, 0.f, 0.f, 0.f}, ac1 = ac0, ac2 = ac0, ac3 = ac0, ac4 = ac0;

  int sf = t >> 4;                 // stage: feature row 0..15 (+16/iter)
  int sc = (t & 15) * 16;          // stage: byte col within 256B row
  int kin = w * 32 + lhi * 8;      // chunk k offset within tile
  int rcol = kin * 2;              // byte col of this lane's B-frag

#pragma unroll 1
  for (int kt = 0; kt < 8; ++kt) {
    // f2 for this tile's chunk: issue early, arrives during stage
    float4 v0 = *(const float4*)(f2p + kt * 128 + kin);
    float4 v1 = *(const float4*)(f2p + kt * 128 + kin + 4);
    __syncthreads();  // previous tile's LDS reads complete
    // ---- stage WhT k-tile into LDS (coalesced, swizzled dest) ----
#pragma unroll
    for (int it = 0; it < 4; ++it) {
      int ff = sf + it * 16;
      const char* src = (const char*)(WhB + (size_t)ff * NTOK + kt * 128) + sc;
      uint4 d = *(const uint4*)src;
      *(uint4*)&wTile[ff * 256 + (sc ^ ((ff & 7) << 4))] = d;
    }
    __syncthreads();  // tile visible (also fences phase A's mLDS on kt=0)

    // ---- compute this wave's K=32 chunk from LDS ----
    s8v bf0 = *(const s8v*)&wTile[(l15) * 256 + (rcol ^ ((l15 & 7) << 4))];
    s8v bf1 = *(const s8v*)&wTile[(16 + l15) * 256 + (rcol ^ ((l15 & 7) << 4))];
    s8v bf2 = *(const s8v*)&wTile[(32 + l15) * 256 + (rcol ^ ((l15 & 7) << 4))];
    s8v bf3 = *(const s8v*)&wTile[(48 + l15) * 256 + (rcol ^ ((l15 & 7) << 4))];
    unsigned byte = mLDS[l15 * 136 + (kt * 4 + w) * 4 + lhi];

    float sv[8] = {f1s * v0.x, f1s * v0.y, f1s * v0.z, f1s * v0.w,
                   f1s * v1.x, f1s * v1.y, f1s * v1.z, f1s * v1.w};
    s8v af;
#pragma unroll
    for (int q = 0; q < 8; ++q) {
      float scv = sv[q];
      float lk = fmaxf(scv, 0.01f * scv);
#if __has_builtin(__builtin_amdgcn_exp2f)
      float pe = __builtin_amdgcn_exp2f(lk - ms);
#else
      float pe = exp2f(lk - ms);
#endif
      float p = (byte & (1u << q)) ? pe : 0.f;
      unsigned uu = __builtin_bit_cast(unsigned, p) + 0x8000u;
      af[q] = (short)(uu >> 16);
    }
    ac0 = __builtin_amdgcn_mfma_f32_16x16x32_bf16(af, bf0, ac0, 0, 0, 0);
    ac1 = __builtin_amdgcn_mfma_f32_16x16x32_bf16(af, bf1, ac1, 0, 0, 0);
    ac2 = __builtin_amdgcn_mfma_f32_16x16x32_bf16(af, bf2, ac2, 0, 0, 0);
    ac3 = __builtin_amdgcn_mfma_f32_16x16x32_bf16(af, bf3, ac3, 0, 0, 0);
    ac4 = __builtin_amdgcn_mfma_f32_16x16x32_bf16(af, bones, ac4, 0, 0, 0);
  }

  // C partials: row = lhi*4+reg, col(feat) = fb*16+l15; row-sums from ac4
#pragma unroll
  for (int reg = 0; reg < 4; ++reg) {
    int row = lhi * 4 + reg;
    float* dst = &red[w * 1088 + row * 68 + l15];
    dst[0] = ac0[reg];
    dst[16] = ac1[reg];
    dst[32] = ac2[reg];
    dst[48] = ac3[reg];
    if (l15 == 0) sums[w * 16 + row] = ac4[reg];
  }
  __syncthreads();

  // write half-K partials (no normalization yet)
  size_t pb = (((size_t)b * 128 + gx) * 2 + hh);
#pragma unroll
  for (int rep = 0; rep < 4; ++rep) {
    int idx = t + rep * 256;
    int mm = idx >> 6, f = idx & 63;
    float v = 0.f, dn = 0.f;
#pragma unroll
    for (int w2 = 0; w2 < 4; ++w2) {
      v += red[w2 * 1088 + mm * 68 + f];
      dn += sums[w2 * 16 + mm];
    }
    part[pb * 1024 + mm * 64 + f] = v;
    if (f == 0) dsum[pb * 16 + mm] = dn;
  }
}

// ---- Kernel C: reduce the two K-halves, normalize, ELU ----
__global__ __launch_bounds__(256) void gat_fin(
    const float* __restrict__ part, const float* __restrict__ dsum,
    float* __restrict__ out) {
  int gx = blockIdx.x, b = blockIdx.y, t = threadIdx.x;
  size_t g = (size_t)b * 128 + gx;
#pragma unroll
  for (int rep = 0; rep < 4; ++rep) {
    int idx = t + rep * 256;
    int mm = idx >> 6, f = idx & 63;
    float v = part[(g * 2) * 1024 + mm * 64 + f] +
              part[(g * 2 + 1) * 1024 + mm * 64 + f];
    float dn = dsum[(g * 2) * 16 + mm] + dsum[(g * 2 + 1) * 16 + mm];
    float rdn = dn > 0.f ? 1.0f / dn : 0.f;
    float hp = v * rdn;
    float o = hp > 0.f ? hp : expm1f(hp);
    out[((size_t)b * NTOK + gx * 16 + mm) * 64 + f] = o;
  }
}

extern "C" void kernel_launch(void* const* d_in, const int* in_sizes, int n_in,
                              void* d_out, int out_size, void* d_ws, size_t ws_size,
                              hipStream_t stream) {
  const float* h = (const float*)d_in[0];
  const int* adj = (const int*)d_in[1];
  const float* W = (const float*)d_in[2];
  const float* a = (const float*)d_in[3];
  float* out = (float*)d_out;

  char* ws = (char*)d_ws;
  unsigned short* WhT = (unsigned short*)ws;            // 2 MB
  float* f1 = (float*)(ws + 2 * 1024 * 1024);           // 64 KB
  float* f2 = f1 + 16384;                               // 64 KB
  unsigned* gmaxk = (unsigned*)(f2 + 16384);            // 32 B
  unsigned* gmink = gmaxk + 8;                          // 32 B
  float* part = (float*)(ws + 3 * 1024 * 1024);         // 8 MB
  float* dsum = (float*)(ws + 12 * 1024 * 1024);        // 128 KB

  gat_init<<<1, 64, 0, stream>>>(gmaxk, gmink);
  gat_pre<<<256, 256, 0, stream>>>(h, W, a, WhT, f1, f2, gmaxk, gmink);
  gat_main<<<dim3(128, 8, 2), 256, 0, stream>>>(adj, WhT, f1, f2, gmaxk, gmink,
                                                part, dsum);
  gat_fin<<<dim3(128, 8), 256, 0, stream>>>(part, dsum, out);
}

// Round 11
// 66.736 us; speedup vs baseline: 1.2492x; 1.0861x over previous
//
#include <hip/hip_runtime.h>

#define NTOK 2048

typedef __attribute__((ext_vector_type(8))) short s8v;
typedef __attribute__((ext_vector_type(4))) float f32x4;

__device__ inline unsigned short f2bf(float f) {
  unsigned u = __builtin_bit_cast(unsigned, f);
  u += 0x7FFFu + ((u >> 16) & 1u);
  return (unsigned short)(u >> 16);
}
__device__ inline unsigned fkey(float f) {
  unsigned u = __builtin_bit_cast(unsigned, f);
  return (u & 0x80000000u) ? ~u : (u | 0x80000000u);
}
__device__ inline float kdec(unsigned k) {
  unsigned u = (k & 0x80000000u) ? (k ^ 0x80000000u) : ~k;
  return __builtin_bit_cast(float, u);
}

// ---- Kernel 0: init the atomic min/max cells (graph-capture safe) ----
__global__ void gat_init(unsigned* gmaxk, unsigned* gmink) {
  int t = threadIdx.x;
  if (t < 8) { gmaxk[t] = 0u; gmink[t] = 0xFFFFFFFFu; }
}

// ---- Kernel A: Wh = h@W, f1/f2 = Wh@a1/a2, WhT = bf16(Wh)^T, f2 min/max ----
__global__ __launch_bounds__(256) void gat_pre(
    const float* __restrict__ h, const float* __restrict__ W,
    const float* __restrict__ a, unsigned short* __restrict__ WhT,
    float* __restrict__ f1, float* __restrict__ f2,
    unsigned* __restrict__ gmaxk, unsigned* __restrict__ gmink) {
  __shared__ float wL[128 * 64];            // 32 KB
  __shared__ float hL[64 * 128];            // 32 KB
  __shared__ unsigned short tL[64 * 66];    // 8.25 KB [feat][tok] pad 66
  __shared__ float bmx[4], bmn[4];
  int t = threadIdx.x;
  {
    const float4* W4 = (const float4*)W;
    float4* wL4 = (float4*)wL;
#pragma unroll
    for (int k = 0; k < 8; ++k) wL4[t + 256 * k] = W4[t + 256 * k];
    const float4* h4 = (const float4*)(h + (size_t)blockIdx.x * 64 * 128);
    float4* hL4 = (float4*)hL;
#pragma unroll
    for (int k = 0; k < 8; ++k) hL4[t + 256 * k] = h4[t + 256 * k];
  }
  __syncthreads();
  int w = t >> 6, lane = t & 63;
  float acc[16];
#pragma unroll
  for (int r = 0; r < 16; ++r) acc[r] = 0.f;
  for (int kc = 0; kc < 128; kc += 32) {
    float wreg[32];
#pragma unroll
    for (int kk = 0; kk < 32; ++kk) wreg[kk] = wL[(kc + kk) * 64 + lane];
#pragma unroll
    for (int r = 0; r < 16; ++r) {
      const float* hrow = &hL[(w * 16 + r) * 128 + kc];
#pragma unroll
      for (int kk = 0; kk < 32; kk += 4) {
        float4 hv = *(const float4*)(hrow + kk);
        acc[r] += hv.x * wreg[kk] + hv.y * wreg[kk + 1] +
                  hv.z * wreg[kk + 2] + hv.w * wreg[kk + 3];
      }
    }
  }
  float a1 = a[lane], a2 = a[lane + 64];
  int row0 = blockIdx.x * 64 + w * 16;
  float wmx = -3.4e38f, wmn = 3.4e38f;
#pragma unroll
  for (int r = 0; r < 16; ++r) {
    float v1 = acc[r] * a1, v2 = acc[r] * a2;
#pragma unroll
    for (int s = 32; s; s >>= 1) {
      v1 += __shfl_xor(v1, s, 64);
      v2 += __shfl_xor(v2, s, 64);
    }
    if (lane == 0) { f1[row0 + r] = v1; f2[row0 + r] = v2; }
    wmx = fmaxf(wmx, v2);
    wmn = fminf(wmn, v2);
    tL[lane * 66 + w * 16 + r] = f2bf(acc[r]);
  }
  if (lane == 0) { bmx[w] = wmx; bmn[w] = wmn; }
  __syncthreads();
  int b = blockIdx.x >> 5;  // 32 blocks per batch
  if (t == 0) {
    float mx = fmaxf(fmaxf(bmx[0], bmx[1]), fmaxf(bmx[2], bmx[3]));
    float mn = fminf(fminf(bmn[0], bmn[1]), fminf(bmn[2], bmn[3]));
    atomicMax(&gmaxk[b], fkey(mx));
    atomicMin(&gmink[b], fkey(mn));
  }
  // WhT[b][feat][tok] write: 4 threads per feature, 64B-contiguous segments
  int tok0 = (blockIdx.x & 31) * 64;
  int f = t >> 2, sub = t & 3;
  const unsigned short* src = &tL[f * 66];
  unsigned short* dst = WhT + ((size_t)b * 64 + f) * NTOK + tok0;
  *(uint4*)(dst + sub * 8) = *(const uint4*)(src + sub * 8);
  *(uint4*)(dst + 32 + sub * 8) = *(const uint4*)(src + 32 + sub * 8);
}

// ---- Kernel B: wave-autonomous fused kernel. grid (16,8,4), 512 thr. ----
// Block (part,b,ks): one startup stage of WhT k-slice (64f x 512k bf16,
// swizzled) + f1/f2 slices into LDS, ONE barrier, then each wave w
// independently processes row-group rg = part*8+w: stream 16 adj rows x
// 512 cols as coalesced int4 batches -> mask bytes in registers -> per
// K=32 chunk: 4 __shfl to fetch mask bytes, exp-in-fragment-layout,
// ds_read_b128 B-frags, 5 MFMAs (4 feat blocks + all-ones denominator).
// No cross-wave reduction: bf16 partials + denom written per (rg,ks).
__global__ __launch_bounds__(512, 2) void gat_main(
    const int* __restrict__ adj, const unsigned short* __restrict__ WhT,
    const float* __restrict__ f1, const float* __restrict__ f2,
    const unsigned* __restrict__ gmaxk, const unsigned* __restrict__ gmink,
    unsigned short* __restrict__ part, float* __restrict__ dsum) {
  __shared__ __align__(16) unsigned char wTile[65536];  // 64f x 512k bf16
  __shared__ float f2L[512];
  __shared__ float f1L[2048];
  int t = threadIdx.x;
  int pt = blockIdx.x, b = blockIdx.y, ks = blockIdx.z;
  int w = t >> 6, lane = t & 63, l15 = lane & 15, lhi = lane >> 4;

  // ---- startup stage (the only barrier) ----
  {
    int ff = t >> 3;
    const char* srow =
        (const char*)(WhT + (size_t)b * 64 * NTOK + (size_t)ff * NTOK + ks * 512);
    int cb0 = (t & 7) * 128;
#pragma unroll
    for (int u = 0; u < 8; ++u) {
      int cb = cb0 + u * 16;
      uint4 d = *(const uint4*)(srow + cb);
      *(uint4*)&wTile[ff * 1024 + (cb ^ ((ff & 7) << 4))] = d;
    }
    ((float4*)f1L)[t] = ((const float4*)(f1 + (size_t)b * NTOK))[t];
    if (t < 128)
      ((float4*)f2L)[t] = ((const float4*)(f2 + (size_t)b * NTOK + ks * 512))[t];
  }
  __syncthreads();

  int rg = pt * 8 + w;
  int i0 = rg * 16;
  const float L2E = 1.44269504f;
  float f1s = f1L[i0 + l15] * L2E;
  float gmx = kdec(gmaxk[b]), gmn = kdec(gmink[b]);
  float mr = fmaxf(f1s * gmx, f1s * gmn);
  float ms = fmaxf(mr, 0.01f * mr);  // log2-scaled safe upper bound

  // ---- mask bytes in registers: lane holds kbyte `lane` of all 16 rows ----
  unsigned d0 = 0, d1 = 0, d2 = 0, d3 = 0;
  const int* abase = adj + ((size_t)b * NTOK + i0) * NTOK + ks * 512;
#pragma unroll
  for (int half = 0; half < 2; ++half) {
    int4 u[8], v[8];
#pragma unroll
    for (int r = 0; r < 8; ++r) {
      const int4* a4 = (const int4*)(abase + (size_t)(half * 8 + r) * NTOK);
      u[r] = a4[lane * 2];
      v[r] = a4[lane * 2 + 1];
    }
    __builtin_amdgcn_sched_barrier(0);  // keep the 16 int4 loads batched
#pragma unroll
    for (int r = 0; r < 8; ++r) {
      unsigned by = (unsigned)(u[r].x > 0) | ((unsigned)(u[r].y > 0) << 1) |
                    ((unsigned)(u[r].z > 0) << 2) | ((unsigned)(u[r].w > 0) << 3) |
                    ((unsigned)(v[r].x > 0) << 4) | ((unsigned)(v[r].y > 0) << 5) |
                    ((unsigned)(v[r].z > 0) << 6) | ((unsigned)(v[r].w > 0) << 7);
      int rr = half * 8 + r;
      if (rr < 4) d0 |= by << ((rr & 3) * 8);
      else if (rr < 8) d1 |= by << ((rr & 3) * 8);
      else if (rr < 12) d2 |= by << ((rr & 3) * 8);
      else d3 |= by << ((rr & 3) * 8);
    }
  }

  const s8v bones = {0x3F80, 0x3F80, 0x3F80, 0x3F80, 0x3F80, 0x3F80, 0x3F80, 0x3F80};
  f32x4 ac0 = {0.f, 0.f, 0.f, 0.f}, ac1 = ac0, ac2 = ac0, ac3 = ac0, ac4 = ac0;
  int sw = (l15 & 7) << 4;

#pragma unroll
  for (int ch = 0; ch < 16; ++ch) {
    int sidx = ch * 4 + lhi;
    unsigned r0 = __shfl(d0, sidx, 64);
    unsigned r1 = __shfl(d1, sidx, 64);
    unsigned r2 = __shfl(d2, sidx, 64);
    unsigned r3 = __shfl(d3, sidx, 64);
    unsigned sel = l15 < 8 ? (l15 < 4 ? r0 : r1) : (l15 < 12 ? r2 : r3);
    unsigned byte = (sel >> ((l15 & 3) * 8)) & 0xFFu;

    float4 v0 = *(const float4*)&f2L[ch * 32 + lhi * 8];
    float4 v1 = *(const float4*)&f2L[ch * 32 + lhi * 8 + 4];
    int kb = ch * 64 + lhi * 16;
    s8v bf0 = *(const s8v*)&wTile[l15 * 1024 + (kb ^ sw)];
    s8v bf1 = *(const s8v*)&wTile[(16 + l15) * 1024 + (kb ^ sw)];
    s8v bf2 = *(const s8v*)&wTile[(32 + l15) * 1024 + (kb ^ sw)];
    s8v bf3 = *(const s8v*)&wTile[(48 + l15) * 1024 + (kb ^ sw)];

    float sv[8] = {f1s * v0.x, f1s * v0.y, f1s * v0.z, f1s * v0.w,
                   f1s * v1.x, f1s * v1.y, f1s * v1.z, f1s * v1.w};
    s8v af;
#pragma unroll
    for (int q = 0; q < 8; ++q) {
      float sc = sv[q];
      float lk = fmaxf(sc, 0.01f * sc);
#if __has_builtin(__builtin_amdgcn_exp2f)
      float pe = __builtin_amdgcn_exp2f(lk - ms);
#else
      float pe = exp2f(lk - ms);
#endif
      float p = (byte & (1u << q)) ? pe : 0.f;
      unsigned uu = __builtin_bit_cast(unsigned, p) + 0x8000u;
      af[q] = (short)(uu >> 16);
    }
    ac0 = __builtin_amdgcn_mfma_f32_16x16x32_bf16(af, bf0, ac0, 0, 0, 0);
    ac1 = __builtin_amdgcn_mfma_f32_16x16x32_bf16(af, bf1, ac1, 0, 0, 0);
    ac2 = __builtin_amdgcn_mfma_f32_16x16x32_bf16(af, bf2, ac2, 0, 0, 0);
    ac3 = __builtin_amdgcn_mfma_f32_16x16x32_bf16(af, bf3, ac3, 0, 0, 0);
    ac4 = __builtin_amdgcn_mfma_f32_16x16x32_bf16(af, bones, ac4, 0, 0, 0);
  }

  // ---- write per-(rg,ks) partials: C rows = lhi*4+reg, cols = fb*16+l15 ----
  size_t pb = ((size_t)(b * 128 + rg)) * 4 + ks;
  unsigned short* pp = part + pb * 1024;
#pragma unroll
  for (int reg = 0; reg < 4; ++reg) {
    int row = lhi * 4 + reg;
    pp[row * 64 + l15] = f2bf(ac0[reg]);
    pp[row * 64 + 16 + l15] = f2bf(ac1[reg]);
    pp[row * 64 + 32 + l15] = f2bf(ac2[reg]);
    pp[row * 64 + 48 + l15] = f2bf(ac3[reg]);
    if (l15 == 0) dsum[pb * 16 + row] = ac4[reg];
  }
}

// ---- Kernel C: reduce 4 K-slices, normalize, ELU ----
__global__ __launch_bounds__(256) void gat_fin(
    const unsigned short* __restrict__ part, const float* __restrict__ dsum,
    float* __restrict__ out) {
  int gx = blockIdx.x, b = blockIdx.y, t = threadIdx.x;
  size_t g = (size_t)b * 128 + gx;
#pragma unroll
  for (int rep = 0; rep < 4; ++rep) {
    int idx = t + rep * 256;
    int mm = idx >> 6, f = idx & 63;
    float v = 0.f, dn = 0.f;
#pragma unroll
    for (int ks = 0; ks < 4; ++ks) {
      size_t pb = g * 4 + ks;
      unsigned us = part[pb * 1024 + mm * 64 + f];
      v += __builtin_bit_cast(float, us << 16);
      dn += dsum[pb * 16 + mm];
    }
    float rdn = dn > 0.f ? 1.0f / dn : 0.f;
    float hp = v * rdn;
    float o = hp > 0.f ? hp : expm1f(hp);
    out[((size_t)b * NTOK + gx * 16 + mm) * 64 + f] = o;
  }
}

extern "C" void kernel_launch(void* const* d_in, const int* in_sizes, int n_in,
                              void* d_out, int out_size, void* d_ws, size_t ws_size,
                              hipStream_t stream) {
  const float* h = (const float*)d_in[0];
  const int* adj = (const int*)d_in[1];
  const float* W = (const float*)d_in[2];
  const float* a = (const float*)d_in[3];
  float* out = (float*)d_out;

  char* ws = (char*)d_ws;
  unsigned short* WhT = (unsigned short*)ws;                // 2 MB
  float* f1 = (float*)(ws + 2 * 1024 * 1024);               // 64 KB
  float* f2 = f1 + 16384;                                   // 64 KB
  unsigned* gmaxk = (unsigned*)(f2 + 16384);                // 32 B
  unsigned* gmink = gmaxk + 8;                              // 32 B
  unsigned short* part = (unsigned short*)(ws + 3 * 1024 * 1024);  // 8 MB bf16
  float* dsum = (float*)(ws + 11 * 1024 * 1024);            // 256 KB

  gat_init<<<1, 64, 0, stream>>>(gmaxk, gmink);
  gat_pre<<<256, 256, 0, stream>>>(h, W, a, WhT, f1, f2, gmaxk, gmink);
  gat_main<<<dim3(16, 8, 4), 512, 0, stream>>>(adj, WhT, f1, f2, gmaxk, gmink,
                                               part, dsum);
  gat_fin<<<dim3(128, 8), 256, 0, stream>>>(part, dsum, out);
}

// Round 12
// 58.708 us; speedup vs baseline: 1.4200x; 1.1367x over previous
//
#include <hip/hip_runtime.h>

#define NTOK 2048

typedef __attribute__((ext_vector_type(8))) short s8v;
typedef __attribute__((ext_vector_type(4))) float f32x4;

__device__ inline unsigned short f2bf(float f) {
  unsigned u = __builtin_bit_cast(unsigned, f);
  u += 0x7FFFu + ((u >> 16) & 1u);
  return (unsigned short)(u >> 16);
}

// ---- Kernel A: Wh = h@W, f1/f2 = Wh@a1/a2, WhT = bf16(Wh)^T, f2 min/max ----
__global__ __launch_bounds__(256) void gat_pre(
    const float* __restrict__ h, const float* __restrict__ W,
    const float* __restrict__ a, unsigned short* __restrict__ WhT,
    float* __restrict__ f1, float* __restrict__ f2,
    float* __restrict__ gmaxs, float* __restrict__ gmins) {
  __shared__ float wL[128 * 64];            // 32 KB
  __shared__ float hL[64 * 128];            // 32 KB
  __shared__ unsigned short tL[64 * 66];    // 8.25 KB [feat][tok] pad 66
  __shared__ float bmx[4], bmn[4];
  int t = threadIdx.x;
  {
    const float4* W4 = (const float4*)W;
    float4* wL4 = (float4*)wL;
#pragma unroll
    for (int k = 0; k < 8; ++k) wL4[t + 256 * k] = W4[t + 256 * k];
    const float4* h4 = (const float4*)(h + (size_t)blockIdx.x * 64 * 128);
    float4* hL4 = (float4*)hL;
#pragma unroll
    for (int k = 0; k < 8; ++k) hL4[t + 256 * k] = h4[t + 256 * k];
  }
  __syncthreads();
  int w = t >> 6, lane = t & 63;
  float acc[16];
#pragma unroll
  for (int r = 0; r < 16; ++r) acc[r] = 0.f;
  for (int kc = 0; kc < 128; kc += 32) {
    float wreg[32];
#pragma unroll
    for (int kk = 0; kk < 32; ++kk) wreg[kk] = wL[(kc + kk) * 64 + lane];
#pragma unroll
    for (int r = 0; r < 16; ++r) {
      const float* hrow = &hL[(w * 16 + r) * 128 + kc];
#pragma unroll
      for (int kk = 0; kk < 32; kk += 4) {
        float4 hv = *(const float4*)(hrow + kk);
        acc[r] += hv.x * wreg[kk] + hv.y * wreg[kk + 1] +
                  hv.z * wreg[kk + 2] + hv.w * wreg[kk + 3];
      }
    }
  }
  float a1 = a[lane], a2 = a[lane + 64];
  int row0 = blockIdx.x * 64 + w * 16;
  float wmx = -3.4e38f, wmn = 3.4e38f;
#pragma unroll
  for (int r = 0; r < 16; ++r) {
    float v1 = acc[r] * a1, v2 = acc[r] * a2;
#pragma unroll
    for (int s = 32; s; s >>= 1) {
      v1 += __shfl_xor(v1, s, 64);
      v2 += __shfl_xor(v2, s, 64);
    }
    if (lane == 0) { f1[row0 + r] = v1; f2[row0 + r] = v2; }
    wmx = fmaxf(wmx, v2);
    wmn = fminf(wmn, v2);
    tL[lane * 66 + w * 16 + r] = f2bf(acc[r]);
  }
  if (lane == 0) { bmx[w] = wmx; bmn[w] = wmn; }
  __syncthreads();
  int b = blockIdx.x >> 5;  // 32 blocks per batch
  if (t == 0) {
    float mx = fmaxf(fmaxf(bmx[0], bmx[1]), fmaxf(bmx[2], bmx[3]));
    float mn = fminf(fminf(bmn[0], bmn[1]), fminf(bmn[2], bmn[3]));
    gmaxs[b * 32 + (blockIdx.x & 31)] = mx;
    gmins[b * 32 + (blockIdx.x & 31)] = mn;
  }
  // WhT[b][feat][tok] write: 4 threads per feature, 64B-contiguous segments
  int tok0 = (blockIdx.x & 31) * 64;
  int f = t >> 2, sub = t & 3;
  const unsigned short* src = &tL[f * 66];
  unsigned short* dst = WhT + ((size_t)b * 64 + f) * NTOK + tok0;
  *(uint4*)(dst + sub * 8) = *(const uint4*)(src + sub * 8);
  *(uint4*)(dst + 32 + sub * 8) = *(const uint4*)(src + 32 + sub * 8);
}

// ---- Kernel B: wave-autonomous fused kernel, asm-forced deep adj stream ----
// grid (16,8,4), 512 thr = 8 waves. Block (part,b,ks): stage WhT k-slice
// (64f x 512k bf16, swizzled) + f2 slice to LDS, ONE barrier; each wave w
// then independently: stream its 16 adj rows x 512 cols via inline-asm
// global_load_dwordx4 batches (8 issued ahead, counted vmcnt(8) waits ->
// compiler cannot collapse depth), pack mask bytes in registers, then 16
// chunks of {4 shfl mask fetch, exp-in-fragment-layout, swizzled
// ds_read_b128 B-frags, 5 MFMAs (4 feat + all-ones denominator)}.
#define LOADX4(dst, va) \
  asm volatile("global_load_dwordx4 %0, %1, off" : "=v"(dst) : "v"(va))
#define WAITV(n) \
  asm volatile("s_waitcnt vmcnt(" #n ")" ::: "memory"); \
  __builtin_amdgcn_sched_barrier(0)
#define PACK4(s0, s1, s2, s3, s4, s5, s6, s7, D)                               \
  {                                                                            \
    unsigned b0 = (unsigned)(s0.x > 0) | ((unsigned)(s0.y > 0) << 1) |         \
                  ((unsigned)(s0.z > 0) << 2) | ((unsigned)(s0.w > 0) << 3) |  \
                  ((unsigned)(s1.x > 0) << 4) | ((unsigned)(s1.y > 0) << 5) |  \
                  ((unsigned)(s1.z > 0) << 6) | ((unsigned)(s1.w > 0) << 7);   \
    unsigned b1 = (unsigned)(s2.x > 0) | ((unsigned)(s2.y > 0) << 1) |         \
                  ((unsigned)(s2.z > 0) << 2) | ((unsigned)(s2.w > 0) << 3) |  \
                  ((unsigned)(s3.x > 0) << 4) | ((unsigned)(s3.y > 0) << 5) |  \
                  ((unsigned)(s3.z > 0) << 6) | ((unsigned)(s3.w > 0) << 7);   \
    unsigned b2 = (unsigned)(s4.x > 0) | ((unsigned)(s4.y > 0) << 1) |         \
                  ((unsigned)(s4.z > 0) << 2) | ((unsigned)(s4.w > 0) << 3) |  \
                  ((unsigned)(s5.x > 0) << 4) | ((unsigned)(s5.y > 0) << 5) |  \
                  ((unsigned)(s5.z > 0) << 6) | ((unsigned)(s5.w > 0) << 7);   \
    unsigned b3 = (unsigned)(s6.x > 0) | ((unsigned)(s6.y > 0) << 1) |         \
                  ((unsigned)(s6.z > 0) << 2) | ((unsigned)(s6.w > 0) << 3) |  \
                  ((unsigned)(s7.x > 0) << 4) | ((unsigned)(s7.y > 0) << 5) |  \
                  ((unsigned)(s7.z > 0) << 6) | ((unsigned)(s7.w > 0) << 7);   \
    D = b0 | (b1 << 8) | (b2 << 16) | (b3 << 24);                              \
  }

__global__ __launch_bounds__(512, 2) void gat_main(
    const int* __restrict__ adj, const unsigned short* __restrict__ WhT,
    const float* __restrict__ f1, const float* __restrict__ f2,
    const float* __restrict__ gmaxs, const float* __restrict__ gmins,
    unsigned short* __restrict__ part, float* __restrict__ dsum) {
  __shared__ __align__(16) unsigned char wTile[65536];  // 64f x 512k bf16
  __shared__ float f2L[512];
  int t = threadIdx.x;
  int pt = blockIdx.x, b = blockIdx.y, ks = blockIdx.z;
  int w = t >> 6, lane = t & 63, l15 = lane & 15, lhi = lane >> 4;

  // ---- startup stage (the only barrier) ----
  {
    int ff = t >> 3;
    const char* srow =
        (const char*)(WhT + (size_t)b * 64 * NTOK + (size_t)ff * NTOK + ks * 512);
    int cb0 = (t & 7) * 128;
#pragma unroll
    for (int u = 0; u < 8; ++u) {
      int cb = cb0 + u * 16;
      uint4 d = *(const uint4*)(srow + cb);
      *(uint4*)&wTile[ff * 1024 + (cb ^ ((ff & 7) << 4))] = d;
    }
    if (t < 128)
      ((float4*)f2L)[t] = ((const float4*)(f2 + (size_t)b * NTOK + ks * 512))[t];
  }
  __syncthreads();

  int rg = pt * 8 + w;
  int i0 = rg * 16;
  const float L2E = 1.44269504f;
  float f1s = f1[(size_t)b * NTOK + i0 + l15] * L2E;
  float gmx = -3.4e38f, gmn = 3.4e38f;
#pragma unroll
  for (int j = 0; j < 32; ++j) {
    gmx = fmaxf(gmx, gmaxs[b * 32 + j]);
    gmn = fminf(gmn, gmins[b * 32 + j]);
  }
  float mr = fmaxf(f1s * gmx, f1s * gmn);
  float ms = fmaxf(mr, 0.01f * mr);  // log2-scaled safe upper bound

  // ---- asm-forced deep adj stream: 16 rows x 2KB, 4 batches of 8 loads ----
  unsigned d0, d1, d2, d3;
  {
    const int* abase = adj + ((size_t)b * NTOK + i0) * NTOK + ks * 512;
    unsigned long long bp = (unsigned long long)abase + (unsigned)(lane * 32);
    int4 A0, A1, A2, A3, A4, A5, A6, A7;
    int4 B0, B1, B2, B3, B4, B5, B6, B7;
    __builtin_amdgcn_sched_barrier(0);
    // batch 0: rows 0-3, batch 1: rows 4-7 (row stride 8192 B)
    LOADX4(A0, bp + 0ull);       LOADX4(A1, bp + 16ull);
    LOADX4(A2, bp + 8192ull);    LOADX4(A3, bp + 8208ull);
    LOADX4(A4, bp + 16384ull);   LOADX4(A5, bp + 16400ull);
    LOADX4(A6, bp + 24576ull);   LOADX4(A7, bp + 24592ull);
    LOADX4(B0, bp + 32768ull);   LOADX4(B1, bp + 32784ull);
    LOADX4(B2, bp + 40960ull);   LOADX4(B3, bp + 40976ull);
    LOADX4(B4, bp + 49152ull);   LOADX4(B5, bp + 49168ull);
    LOADX4(B6, bp + 57344ull);   LOADX4(B7, bp + 57360ull);
    WAITV(8);
    PACK4(A0, A1, A2, A3, A4, A5, A6, A7, d0);
    LOADX4(A0, bp + 65536ull);   LOADX4(A1, bp + 65552ull);
    LOADX4(A2, bp + 73728ull);   LOADX4(A3, bp + 73744ull);
    LOADX4(A4, bp + 81920ull);   LOADX4(A5, bp + 81936ull);
    LOADX4(A6, bp + 90112ull);   LOADX4(A7, bp + 90128ull);
    WAITV(8);
    PACK4(B0, B1, B2, B3, B4, B5, B6, B7, d1);
    LOADX4(B0, bp + 98304ull);   LOADX4(B1, bp + 98320ull);
    LOADX4(B2, bp + 106496ull);  LOADX4(B3, bp + 106512ull);
    LOADX4(B4, bp + 114688ull);  LOADX4(B5, bp + 114704ull);
    LOADX4(B6, bp + 122880ull);  LOADX4(B7, bp + 122896ull);
    WAITV(8);
    PACK4(A0, A1, A2, A3, A4, A5, A6, A7, d2);
    WAITV(0);
    PACK4(B0, B1, B2, B3, B4, B5, B6, B7, d3);
    __builtin_amdgcn_sched_barrier(0);
  }

  const s8v bones = {0x3F80, 0x3F80, 0x3F80, 0x3F80, 0x3F80, 0x3F80, 0x3F80, 0x3F80};
  f32x4 ac0 = {0.f, 0.f, 0.f, 0.f}, ac1 = ac0, ac2 = ac0, ac3 = ac0, ac4 = ac0;
  int sw = (l15 & 7) << 4;

#pragma unroll
  for (int ch = 0; ch < 16; ++ch) {
    int sidx = ch * 4 + lhi;
    unsigned r0 = __shfl(d0, sidx, 64);
    unsigned r1 = __shfl(d1, sidx, 64);
    unsigned r2 = __shfl(d2, sidx, 64);
    unsigned r3 = __shfl(d3, sidx, 64);
    unsigned sel = l15 < 8 ? (l15 < 4 ? r0 : r1) : (l15 < 12 ? r2 : r3);
    unsigned byte = (sel >> ((l15 & 3) * 8)) & 0xFFu;

    float4 v0 = *(const float4*)&f2L[ch * 32 + lhi * 8];
    float4 v1 = *(const float4*)&f2L[ch * 32 + lhi * 8 + 4];
    int kb = ch * 64 + lhi * 16;
    s8v bf0 = *(const s8v*)&wTile[l15 * 1024 + (kb ^ sw)];
    s8v bf1 = *(const s8v*)&wTile[(16 + l15) * 1024 + (kb ^ sw)];
    s8v bf2 = *(const s8v*)&wTile[(32 + l15) * 1024 + (kb ^ sw)];
    s8v bf3 = *(const s8v*)&wTile[(48 + l15) * 1024 + (kb ^ sw)];

    float sv[8] = {f1s * v0.x, f1s * v0.y, f1s * v0.z, f1s * v0.w,
                   f1s * v1.x, f1s * v1.y, f1s * v1.z, f1s * v1.w};
    s8v af;
#pragma unroll
    for (int q = 0; q < 8; ++q) {
      float sc = sv[q];
      float lk = fmaxf(sc, 0.01f * sc);
#if __has_builtin(__builtin_amdgcn_exp2f)
      float pe = __builtin_amdgcn_exp2f(lk - ms);
#else
      float pe = exp2f(lk - ms);
#endif
      float p = (byte & (1u << q)) ? pe : 0.f;
      unsigned uu = __builtin_bit_cast(unsigned, p) + 0x8000u;
      af[q] = (short)(uu >> 16);
    }
    ac0 = __builtin_amdgcn_mfma_f32_16x16x32_bf16(af, bf0, ac0, 0, 0, 0);
    ac1 = __builtin_amdgcn_mfma_f32_16x16x32_bf16(af, bf1, ac1, 0, 0, 0);
    ac2 = __builtin_amdgcn_mfma_f32_16x16x32_bf16(af, bf2, ac2, 0, 0, 0);
    ac3 = __builtin_amdgcn_mfma_f32_16x16x32_bf16(af, bf3, ac3, 0, 0, 0);
    ac4 = __builtin_amdgcn_mfma_f32_16x16x32_bf16(af, bones, ac4, 0, 0, 0);
  }

  // ---- write per-(rg,ks) partials: C rows = lhi*4+reg, cols = fb*16+l15 ----
  size_t pb = ((size_t)(b * 128 + rg)) * 4 + ks;
  unsigned short* pp = part + pb * 1024;
#pragma unroll
  for (int reg = 0; reg < 4; ++reg) {
    int row = lhi * 4 + reg;
    pp[row * 64 + l15] = f2bf(ac0[reg]);
    pp[row * 64 + 16 + l15] = f2bf(ac1[reg]);
    pp[row * 64 + 32 + l15] = f2bf(ac2[reg]);
    pp[row * 64 + 48 + l15] = f2bf(ac3[reg]);
    if (l15 == 0) dsum[pb * 16 + row] = ac4[reg];
  }
}

// ---- Kernel C: reduce 4 K-slices, normalize, ELU ----
__global__ __launch_bounds__(256) void gat_fin(
    const unsigned short* __restrict__ part, const float* __restrict__ dsum,
    float* __restrict__ out) {
  int gx = blockIdx.x, b = blockIdx.y, t = threadIdx.x;
  size_t g = (size_t)b * 128 + gx;
#pragma unroll
  for (int rep = 0; rep < 4; ++rep) {
    int idx = t + rep * 256;
    int mm = idx >> 6, f = idx & 63;
    float v = 0.f, dn = 0.f;
#pragma unroll
    for (int ks = 0; ks < 4; ++ks) {
      size_t pb = g * 4 + ks;
      unsigned us = part[pb * 1024 + mm * 64 + f];
      v += __builtin_bit_cast(float, us << 16);
      dn += dsum[pb * 16 + mm];
    }
    float rdn = dn > 0.f ? 1.0f / dn : 0.f;
    float hp = v * rdn;
    float o = hp > 0.f ? hp : expm1f(hp);
    out[((size_t)b * NTOK + gx * 16 + mm) * 64 + f] = o;
  }
}

extern "C" void kernel_launch(void* const* d_in, const int* in_sizes, int n_in,
                              void* d_out, int out_size, void* d_ws, size_t ws_size,
                              hipStream_t stream) {
  const float* h = (const float*)d_in[0];
  const int* adj = (const int*)d_in[1];
  const float* W = (const float*)d_in[2];
  const float* a = (const float*)d_in[3];
  float* out = (float*)d_out;

  char* ws = (char*)d_ws;
  unsigned short* WhT = (unsigned short*)ws;                // 2 MB
  float* f1 = (float*)(ws + 2 * 1024 * 1024);               // 64 KB
  float* f2 = f1 + 16384;                                   // 64 KB
  float* gmaxs = (float*)(f2 + 16384);                      // 1 KB
  float* gmins = gmaxs + 256;                               // 1 KB
  unsigned short* part = (unsigned short*)(ws + 3 * 1024 * 1024);  // 8 MB bf16
  float* dsum = (float*)(ws + 11 * 1024 * 1024);            // 256 KB

  gat_pre<<<256, 256, 0, stream>>>(h, W, a, WhT, f1, f2, gmaxs, gmins);
  gat_main<<<dim3(16, 8, 4), 512, 0, stream>>>(adj, WhT, f1, f2, gmaxs, gmins,
                                               part, dsum);
  gat_fin<<<dim3(128, 8), 256, 0, stream>>>(part, dsum, out);
}